// Round 10
// baseline (98.338 us; speedup 1.0000x reference)
//
#include <hip/hip_runtime.h>
#include <math.h>

// probs/targets: (32,1,512,512) fp32
// ROUND 10 = DIAGNOSTIC. Production path == r9 (best 19.14us), plus:
//  - k_diag: r9 streaming body x8 over rotated chunks -> ~50-70us dispatch,
//    cracks rocprof top-5 -> read VALUBusy/Occupancy/FETCH of our hot loop.
//  - k_final launched 3x (idempotent) -> T_f = (dur - 19.14 - T_diag)/2.
// Decision tree pre-committed in journal; production numbers unaffected.
#define NS 32
#define NELEM 262144
#define PBLK 16               // partial blocks per sample
#define GRID (NS * PBLK)      // 512 blocks
#define TPB 256               // 4 waves
#define CHUNK (NELEM / PBLK)  // 16384 elements per block; 64 per thread

#define NPART (NS * PBLK)     // 512 partial sets
#define OFF_S1   0
#define OFF_S2   (NPART * 1)
#define OFF_DOT  (NPART * 2)
#define OFF_MX   (NPART * 3)
#define OFF_CGT  (NPART * 4)
#define OFF_PK   (NPART * 5)
// diag scratch (never read by k_final)
#define OFF_DF   (NPART * 8)   // 4 float quantities, stride NPART
#define OFF_DI   (NPART * 12)  // 2 int quantities, stride NPART

__device__ __forceinline__ void comb(float& mx, int& pk, float m2, int pk2) {
    const bool g = m2 > mx;
    const bool e = m2 == mx;
    pk = g ? pk2 : (pk + (e ? pk2 : 0));
    mx = fmaxf(mx, m2);
}

struct Acc {
    float4 a1, a2, ad;
    int cgt;
    float mx;
    int pk;
};

__device__ __forceinline__ void consume(Acc& A, const float4 (&pv)[4],
                                        const float4 (&tv)[4]) {
#pragma unroll
    for (int k = 0; k < 4; ++k) {
        A.a1.x += pv[k].x; A.a1.y += pv[k].y; A.a1.z += pv[k].z; A.a1.w += pv[k].w;
        A.a2.x += tv[k].x; A.a2.y += tv[k].y; A.a2.z += tv[k].z; A.a2.w += tv[k].w;
        A.ad.x = fmaf(pv[k].x, tv[k].x, A.ad.x);
        A.ad.y = fmaf(pv[k].y, tv[k].y, A.ad.y);
        A.ad.z = fmaf(pv[k].z, tv[k].z, A.ad.z);
        A.ad.w = fmaf(pv[k].w, tv[k].w, A.ad.w);
    }
    const float mX = fmaxf(fmaxf(tv[0].x, tv[1].x), fmaxf(tv[2].x, tv[3].x));
    const float mY = fmaxf(fmaxf(tv[0].y, tv[1].y), fmaxf(tv[2].y, tv[3].y));
    const float mZ = fmaxf(fmaxf(tv[0].z, tv[1].z), fmaxf(tv[2].z, tv[3].z));
    const float mW = fmaxf(fmaxf(tv[0].w, tv[1].w), fmaxf(tv[2].w, tv[3].w));
    const float mg = fmaxf(fmaxf(mX, mY), fmaxf(mZ, mW));
    int cp = 0, cg = 0, gg = 0;
#pragma unroll
    for (int k = 0; k < 4; ++k) {
        const float pc[4] = {pv[k].x, pv[k].y, pv[k].z, pv[k].w};
        const float tc[4] = {tv[k].x, tv[k].y, tv[k].z, tv[k].w};
#pragma unroll
        for (int j = 0; j < 4; ++j) {
            const int b1 = pc[j] > 0.5f;
            const int eq = tc[j] == mg;
            cp += b1;
            cg += eq;
            gg += eq & b1;
        }
    }
    A.cgt += cp;
    comb(A.mx, A.pk, mg, (cg << 16) | gg);
}

// r9 streaming body: 64 elem/thread with A/B register double-buffer
__device__ __forceinline__ void stream_chunk(const float4* __restrict__ p4,
                                             const float4* __restrict__ t4,
                                             int t, Acc& A) {
    float4 pA[4], tA[4], pB[4], tB[4];
#pragma unroll
    for (int k = 0; k < 4; ++k) { pA[k] = p4[k*256 + t];        tA[k] = t4[k*256 + t]; }
#pragma unroll
    for (int k = 0; k < 4; ++k) { pB[k] = p4[1024 + k*256 + t]; tB[k] = t4[1024 + k*256 + t]; }
    consume(A, pA, tA);
#pragma unroll
    for (int k = 0; k < 4; ++k) { pA[k] = p4[2048 + k*256 + t]; tA[k] = t4[2048 + k*256 + t]; }
    consume(A, pB, tB);
#pragma unroll
    for (int k = 0; k < 4; ++k) { pB[k] = p4[3072 + k*256 + t]; tB[k] = t4[3072 + k*256 + t]; }
    consume(A, pA, tA);
    consume(A, pB, tB);
}

__device__ __forceinline__ void block_reduce_store(Acc& A, int t, int b,
                                                   float* __restrict__ wsf,
                                                   int* __restrict__ wsi,
                                                   int of_f, int of_i) {
    float s1 = (A.a1.x + A.a1.y) + (A.a1.z + A.a1.w);
    float s2 = (A.a2.x + A.a2.y) + (A.a2.z + A.a2.w);
    float dt = (A.ad.x + A.ad.y) + (A.ad.z + A.ad.w);
    int cgt = A.cgt;
    float mxr = A.mx;
    int pkr = A.pk;

#pragma unroll
    for (int off = 32; off; off >>= 1) {
        s1  += __shfl_xor(s1, off);
        s2  += __shfl_xor(s2, off);
        dt  += __shfl_xor(dt, off);
        cgt += __shfl_xor(cgt, off);
        const float m2 = __shfl_xor(mxr, off);
        const int  pk2 = __shfl_xor(pkr, off);
        comb(mxr, pkr, m2, pk2);
    }

    __shared__ float ls1[4], ls2[4], ldt[4], lmx[4];
    __shared__ int   lcg[4], lpk[4];
    const int w = t >> 6, lane = t & 63;
    if (lane == 0) {
        ls1[w] = s1; ls2[w] = s2; ldt[w] = dt; lmx[w] = mxr;
        lcg[w] = cgt; lpk[w] = pkr;
    }
    __syncthreads();
    if (t == 0) {
#pragma unroll
        for (int w2 = 1; w2 < TPB / 64; ++w2) {
            s1 += ls1[w2]; s2 += ls2[w2]; dt += ldt[w2]; cgt += lcg[w2];
            comb(mxr, pkr, lmx[w2], lpk[w2]);
        }
        wsf[of_f + NPART * 0 + b] = s1;
        wsf[of_f + NPART * 1 + b] = s2;
        wsf[of_f + NPART * 2 + b] = dt;
        wsf[of_f + NPART * 3 + b] = mxr;
        wsi[of_i + NPART * 0 + b] = cgt;
        wsi[of_i + NPART * 1 + b] = pkr;
    }
}

__global__ __launch_bounds__(TPB) void k_partial(const float* __restrict__ probs,
                                                 const float* __restrict__ tgts,
                                                 float* __restrict__ wsf,
                                                 int* __restrict__ wsi) {
    const int b = blockIdx.x;
    const int s = b >> 4;
    const int c = b & (PBLK - 1);
    const size_t base = (size_t)s * NELEM + (size_t)c * CHUNK;
    const int t = threadIdx.x;

    Acc A;
    A.a1 = {0.f,0.f,0.f,0.f}; A.a2 = {0.f,0.f,0.f,0.f}; A.ad = {0.f,0.f,0.f,0.f};
    A.cgt = 0; A.mx = -INFINITY; A.pk = 0;

    stream_chunk((const float4*)(probs + base), (const float4*)(tgts + base), t, A);
    block_reduce_store(A, t, b, wsf, wsi, OFF_S1, OFF_CGT);
}

// DIAGNOSTIC: same body x8 over rotated chunks (L3-class traffic each rep),
// accumulated across reps (keeps all reps live vs DCE), stored to scratch.
__global__ __launch_bounds__(TPB) void k_diag(const float* __restrict__ probs,
                                              const float* __restrict__ tgts,
                                              float* __restrict__ wsf,
                                              int* __restrict__ wsi) {
    const int b = blockIdx.x;
    const int s = b >> 4;
    const int c = b & (PBLK - 1);
    const int t = threadIdx.x;

    Acc A;
    A.a1 = {0.f,0.f,0.f,0.f}; A.a2 = {0.f,0.f,0.f,0.f}; A.ad = {0.f,0.f,0.f,0.f};
    A.cgt = 0; A.mx = -INFINITY; A.pk = 0;

#pragma unroll 1
    for (int rep = 0; rep < 8; ++rep) {
        const int c2 = (c + rep) & (PBLK - 1);
        const size_t base = (size_t)s * NELEM + (size_t)c2 * CHUNK;
        stream_chunk((const float4*)(probs + base), (const float4*)(tgts + base), t, A);
    }
    block_reduce_store(A, t, b, wsf, wsi, OFF_DF, OFF_DI);
}

__device__ __forceinline__ void combine_max(float& mx, int& cnt, int& gt,
                                            float mx2, int cnt2, int gt2) {
    if (mx2 > mx) { mx = mx2; cnt = cnt2; gt = gt2; }
    else if (mx2 == mx) { cnt += cnt2; gt += gt2; }
}

__global__ __launch_bounds__(512) void k_final(const float* __restrict__ wsf,
                                               const int* __restrict__ wsi,
                                               float* __restrict__ out) {
    __shared__ float scores[NS];
    const int t = threadIdx.x;
    const int w = t >> 6, lane = t & 63;
    const int samp = (w << 2) + (lane >> 4);
    const int pidx = lane & 15;
    const int idx = samp * PBLK + pidx;

    float s1  = wsf[OFF_S1  + idx];
    float s2  = wsf[OFF_S2  + idx];
    float dot = wsf[OFF_DOT + idx];
    float mx  = wsf[OFF_MX  + idx];
    int   cgt = wsi[OFF_CGT + idx];
    const int pk = wsi[OFF_PK + idx];
    int   cnt = pk >> 16;
    int   gt  = pk & 0xFFFF;

#pragma unroll
    for (int off = 8; off; off >>= 1) {
        s1  += __shfl_xor(s1, off);
        s2  += __shfl_xor(s2, off);
        dot += __shfl_xor(dot, off);
        cgt += __shfl_xor(cgt, off);
        float m2 = __shfl_xor(mx, off);
        int   c2 = __shfl_xor(cnt, off);
        int   g2 = __shfl_xor(gt, off);
        combine_max(mx, cnt, gt, m2, c2, g2);
    }

    if (pidx == 0) {
        const int cle = NELEM - cgt;
        const long long corr = (long long)cle - (long long)cnt + 2LL * (long long)gt;
        float score = 2.0f * (dot + 1.0f) / (s1 + s2 + 1.0f);
        if (corr == 1) score = 1.0f;   // acc == 1.0 (probs.shape[1] == 1)
        scores[samp] = 1.0f - score;
    }

    __syncthreads();
    if (t < 64) {
        float v = (t < NS) ? scores[t] : 0.0f;
#pragma unroll
        for (int off = 32; off; off >>= 1) v += __shfl_xor(v, off);
        if (t == 0) out[0] = v * (1.0f / (float)NS);
    }
}

extern "C" void kernel_launch(void* const* d_in, const int* in_sizes, int n_in,
                              void* d_out, int out_size, void* d_ws, size_t ws_size,
                              hipStream_t stream) {
    const float* probs = (const float*)d_in[0];
    const float* tgts  = (const float*)d_in[1];
    float* wsf = (float*)d_ws;
    int*   wsi = (int*)d_ws;
    float* out = (float*)d_out;

    k_partial<<<GRID, TPB, 0, stream>>>(probs, tgts, wsf, wsi);
    k_diag<<<GRID, TPB, 0, stream>>>(probs, tgts, wsf, wsi);   // diagnostic only
    k_final<<<1, 512, 0, stream>>>(wsf, wsi, out);             // x3 -> measures T_f
    k_final<<<1, 512, 0, stream>>>(wsf, wsi, out);
    k_final<<<1, 512, 0, stream>>>(wsf, wsi, out);
}

// Round 11
// 19.904 us; speedup vs baseline: 4.9406x; 4.9406x over previous
//
#include <hip/hip_runtime.h>
#include <math.h>

// probs/targets: (32,1,512,512) fp32
// ROUND 11: r9 body at 1024 blocks x 32 elem/thread (16 waves/CU).
// r10 diag: streaming BW scales with occupancy (8w/CU ~7TB/s vs 32w/CU
// 13.7TB/s probe), DS tail scales against it (r6: 3.2us at 32w/CU).
// 16 waves/CU is the knee. This is r8's geometry WITHOUT the ballot poison.
#define NS 32
#define NELEM 262144
#define PBLK 32               // partial blocks per sample
#define GRID (NS * PBLK)      // 1024 blocks -> 4 blocks/CU -> 16 waves/CU
#define TPB 256               // 4 waves
#define CHUNK (NELEM / PBLK)  // 8192 elements per block; 32 per thread

#define NPART (NS * PBLK)     // 1024 partial sets
#define OFF_S1   0
#define OFF_S2   (NPART * 1)
#define OFF_DOT  (NPART * 2)
#define OFF_MX   (NPART * 3)
#define OFF_CGT  (NPART * 4)  // int: count(p > 0.5)
#define OFF_PK   (NPART * 5)  // int: (cnt_at_max << 16) | gt_at_max

// branch-free (mx,pk) semigroup combine; 16-bit fields hold block-scope counts
__device__ __forceinline__ void comb(float& mx, int& pk, float m2, int pk2) {
    const bool g = m2 > mx;
    const bool e = m2 == mx;
    pk = g ? pk2 : (pk + (e ? pk2 : 0));
    mx = fmaxf(mx, m2);
}

struct Acc {
    float4 a1, a2, ad;
    int cgt;
    float mx;
    int pk;
};

__device__ __forceinline__ void consume(Acc& A, const float4 (&pv)[4],
                                        const float4 (&tv)[4]) {
    // sums — component-parallel, no scalar chains
#pragma unroll
    for (int k = 0; k < 4; ++k) {
        A.a1.x += pv[k].x; A.a1.y += pv[k].y; A.a1.z += pv[k].z; A.a1.w += pv[k].w;
        A.a2.x += tv[k].x; A.a2.y += tv[k].y; A.a2.z += tv[k].z; A.a2.w += tv[k].w;
        A.ad.x = fmaf(pv[k].x, tv[k].x, A.ad.x);
        A.ad.y = fmaf(pv[k].y, tv[k].y, A.ad.y);
        A.ad.z = fmaf(pv[k].z, tv[k].z, A.ad.z);
        A.ad.w = fmaf(pv[k].w, tv[k].w, A.ad.w);
    }
    // group max via pairwise tree (depth 4)
    const float mX = fmaxf(fmaxf(tv[0].x, tv[1].x), fmaxf(tv[2].x, tv[3].x));
    const float mY = fmaxf(fmaxf(tv[0].y, tv[1].y), fmaxf(tv[2].y, tv[3].y));
    const float mZ = fmaxf(fmaxf(tv[0].z, tv[1].z), fmaxf(tv[2].z, tv[3].z));
    const float mW = fmaxf(fmaxf(tv[0].w, tv[1].w), fmaxf(tv[2].w, tv[3].w));
    const float mg = fmaxf(fmaxf(mX, mY), fmaxf(mZ, mW));
    // branch-free recount vs group max
    int cp = 0, cg = 0, gg = 0;
#pragma unroll
    for (int k = 0; k < 4; ++k) {
        const float pc[4] = {pv[k].x, pv[k].y, pv[k].z, pv[k].w};
        const float tc[4] = {tv[k].x, tv[k].y, tv[k].z, tv[k].w};
#pragma unroll
        for (int j = 0; j < 4; ++j) {
            const int b1 = pc[j] > 0.5f;
            const int eq = tc[j] == mg;
            cp += b1;
            cg += eq;
            gg += eq & b1;
        }
    }
    A.cgt += cp;
    comb(A.mx, A.pk, mg, (cg << 16) | gg);
}

__global__ __launch_bounds__(TPB) void k_partial(const float* __restrict__ probs,
                                                 const float* __restrict__ tgts,
                                                 float* __restrict__ wsf,
                                                 int* __restrict__ wsi) {
    const int b = blockIdx.x;
    const int s = b >> 5;           // sample
    const int c = b & (PBLK - 1);   // chunk within sample
    const size_t base = (size_t)s * NELEM + (size_t)c * CHUNK;
    const float4* __restrict__ p4 = (const float4*)(probs + base);
    const float4* __restrict__ t4 = (const float4*)(tgts + base);
    const int t = threadIdx.x;

    Acc A;
    A.a1 = {0.f,0.f,0.f,0.f}; A.a2 = {0.f,0.f,0.f,0.f}; A.ad = {0.f,0.f,0.f,0.f};
    A.cgt = 0; A.mx = -INFINITY; A.pk = 0;

    // register double-buffer across the 2 groups (32 elem/thread total)
    float4 pA[4], tA[4], pB[4], tB[4];
#pragma unroll
    for (int k = 0; k < 4; ++k) { pA[k] = p4[k*256 + t];        tA[k] = t4[k*256 + t]; }
#pragma unroll
    for (int k = 0; k < 4; ++k) { pB[k] = p4[1024 + k*256 + t]; tB[k] = t4[1024 + k*256 + t]; }
    consume(A, pA, tA);
    consume(A, pB, tB);

    float s1 = (A.a1.x + A.a1.y) + (A.a1.z + A.a1.w);
    float s2 = (A.a2.x + A.a2.y) + (A.a2.z + A.a2.w);
    float dt = (A.ad.x + A.ad.y) + (A.ad.z + A.ad.w);
    int cgt = A.cgt;
    float mxr = A.mx;
    int pkr = A.pk;

    // wave butterfly: 6 quantities x 6 levels
#pragma unroll
    for (int off = 32; off; off >>= 1) {
        s1  += __shfl_xor(s1, off);
        s2  += __shfl_xor(s2, off);
        dt  += __shfl_xor(dt, off);
        cgt += __shfl_xor(cgt, off);
        const float m2 = __shfl_xor(mxr, off);
        const int  pk2 = __shfl_xor(pkr, off);
        comb(mxr, pkr, m2, pk2);
    }

    // cross-wave via LDS (4 waves)
    __shared__ float ls1[4], ls2[4], ldt[4], lmx[4];
    __shared__ int   lcg[4], lpk[4];
    const int w = t >> 6, lane = t & 63;
    if (lane == 0) {
        ls1[w] = s1; ls2[w] = s2; ldt[w] = dt; lmx[w] = mxr;
        lcg[w] = cgt; lpk[w] = pkr;
    }
    __syncthreads();
    if (t == 0) {
#pragma unroll
        for (int w2 = 1; w2 < TPB / 64; ++w2) {
            s1 += ls1[w2]; s2 += ls2[w2]; dt += ldt[w2]; cgt += lcg[w2];
            comb(mxr, pkr, lmx[w2], lpk[w2]);
        }
        wsf[OFF_S1  + b] = s1;
        wsf[OFF_S2  + b] = s2;
        wsf[OFF_DOT + b] = dt;
        wsf[OFF_MX  + b] = mxr;
        wsi[OFF_CGT + b] = cgt;
        wsi[OFF_PK  + b] = pkr;
    }
}

__device__ __forceinline__ void combine_max(float& mx, int& cnt, int& gt,
                                            float mx2, int cnt2, int gt2) {
    if (mx2 > mx) { mx = mx2; cnt = cnt2; gt = gt2; }
    else if (mx2 == mx) { cnt += cnt2; gt += gt2; }
}

// finalize + mean: 1024 threads (16 waves); wave w reduces samples 2w,2w+1
// (32 partials each, one per 32-lane half).
__global__ __launch_bounds__(1024) void k_final(const float* __restrict__ wsf,
                                                const int* __restrict__ wsi,
                                                float* __restrict__ out) {
    __shared__ float scores[NS];
    const int t = threadIdx.x;
    const int w = t >> 6, lane = t & 63;
    const int samp = 2 * w + (lane >> 5);
    const int pidx = lane & 31;
    const int idx = samp * PBLK + pidx;

    float s1  = wsf[OFF_S1  + idx];
    float s2  = wsf[OFF_S2  + idx];
    float dot = wsf[OFF_DOT + idx];
    float mx  = wsf[OFF_MX  + idx];
    int   cgt = wsi[OFF_CGT + idx];
    const int pk = wsi[OFF_PK + idx];
    int   cnt = pk >> 16;      // unpack: sample-level counts exceed 16 bits
    int   gt  = pk & 0xFFFF;

#pragma unroll
    for (int off = 16; off; off >>= 1) {   // stays within 32-lane group
        s1  += __shfl_xor(s1, off);
        s2  += __shfl_xor(s2, off);
        dot += __shfl_xor(dot, off);
        cgt += __shfl_xor(cgt, off);
        float m2 = __shfl_xor(mx, off);
        int   c2 = __shfl_xor(cnt, off);
        int   g2 = __shfl_xor(gt, off);
        combine_max(mx, cnt, gt, m2, c2, g2);
    }

    if (pidx == 0) {
        const int cle = NELEM - cgt;       // count(p <= 0.5)
        const long long corr = (long long)cle - (long long)cnt + 2LL * (long long)gt;
        float score = 2.0f * (dot + 1.0f) / (s1 + s2 + 1.0f);
        if (corr == 1) score = 1.0f;       // acc == 1.0 (probs.shape[1] == 1)
        scores[samp] = 1.0f - score;
    }

    __syncthreads();
    if (t < 64) {
        float v = (t < NS) ? scores[t] : 0.0f;
#pragma unroll
        for (int off = 32; off; off >>= 1) v += __shfl_xor(v, off);
        if (t == 0) out[0] = v * (1.0f / (float)NS);
    }
}

extern "C" void kernel_launch(void* const* d_in, const int* in_sizes, int n_in,
                              void* d_out, int out_size, void* d_ws, size_t ws_size,
                              hipStream_t stream) {
    const float* probs = (const float*)d_in[0];
    const float* tgts  = (const float*)d_in[1];
    float* wsf = (float*)d_ws;
    int*   wsi = (int*)d_ws;
    float* out = (float*)d_out;

    k_partial<<<GRID, TPB, 0, stream>>>(probs, tgts, wsf, wsi);
    k_final<<<1, 1024, 0, stream>>>(wsf, wsi, out);
}